// Round 1
// baseline (41.807 us; speedup 1.0000x reference)
//
#include <hip/hip_runtime.h>
#include <hip/hip_bf16.h>
#include <math.h>

// Problem constants (from reference): S=1000, C=100, L=50, B=20, K=64, N=16384
#define CC 100
#define LL 50
#define BB 20
#define KK 64

// ---------------------------------------------------------------------------
// Kernel 1: build Q [C,B] = softmax_row(P*P_A+P_B)^T @ (softmax_col(D*D_A+D_B) @ P_C)
// Single block, 256 threads. Tiny problem (K=64, C=100, B=20).
// ---------------------------------------------------------------------------
__global__ __launch_bounds__(256) void compute_q_kernel(
    const float* __restrict__ P, const float* __restrict__ D,
    const float* __restrict__ P_A, const float* __restrict__ P_B,
    const float* __restrict__ P_C, const float* __restrict__ D_A,
    const float* __restrict__ D_B, float* __restrict__ Q)
{
    __shared__ float Pm[KK * CC];   // 64*100 = 6400 floats
    __shared__ float Dm[KK * BB];   // 64*20
    __shared__ float E [KK * BB];
    __shared__ float PC[BB * BB];   // 20*20
    const int t = threadIdx.x;

    for (int i = t; i < KK * CC; i += 256) Pm[i] = P[i] * P_A[i] + P_B[i];
    for (int i = t; i < KK * BB; i += 256) Dm[i] = D[i] * D_A[i] + D_B[i];
    for (int i = t; i < BB * BB; i += 256) PC[i] = P_C[i];
    __syncthreads();

    // Row softmax of Pm over C: thread k handles row k.
    if (t < KK) {
        float m = -INFINITY;
        for (int c = 0; c < CC; ++c) m = fmaxf(m, Pm[t * CC + c]);
        float s = 0.f;
        for (int c = 0; c < CC; ++c) { float e = __expf(Pm[t * CC + c] - m); Pm[t * CC + c] = e; s += e; }
        float inv = 1.f / s;
        for (int c = 0; c < CC; ++c) Pm[t * CC + c] *= inv;
    }
    // Column softmax of Dm over K: threads 64..83 handle column b = t-64.
    else if (t < KK + BB) {
        const int b = t - KK;
        float m = -INFINITY;
        for (int k = 0; k < KK; ++k) m = fmaxf(m, Dm[k * BB + b]);
        float s = 0.f;
        for (int k = 0; k < KK; ++k) { float e = __expf(Dm[k * BB + b] - m); Dm[k * BB + b] = e; s += e; }
        float inv = 1.f / s;
        for (int k = 0; k < KK; ++k) Dm[k * BB + b] *= inv;
    }
    __syncthreads();

    // E = Dm @ P_C  : [K,B]
    for (int i = t; i < KK * BB; i += 256) {
        const int k = i / BB, b = i % BB;
        float acc = 0.f;
        for (int j = 0; j < BB; ++j) acc += Dm[k * BB + j] * PC[j * BB + b];
        E[i] = acc;
    }
    __syncthreads();

    // Q[c,b] = sum_k Pm[k,c] * E[k,b]  : [C,B]
    for (int i = t; i < CC * BB; i += 256) {
        const int c = i / BB, b = i % BB;
        float acc = 0.f;
        for (int k = 0; k < KK; ++k) acc += Pm[k * CC + c] * E[k * BB + b];
        Q[i] = acc;
    }
}

// ---------------------------------------------------------------------------
// Kernel 2: per-sample gather + column-softmax + matvec + blend.
// One block per sample n (grid = N), 128 threads.
// ---------------------------------------------------------------------------
__global__ __launch_bounds__(128) void main_kernel(
    const float* __restrict__ X, const int* __restrict__ stu,
    const int* __restrict__ cour, const float* __restrict__ csa,
    const float* __restrict__ Q, const float* __restrict__ guess_,
    const float* __restrict__ slide_, float* __restrict__ out)
{
    const int n = blockIdx.x;
    __shared__ float V[LL * BB];   // 1000 floats, the csa[stu[n],cour[n]] slice
    __shared__ float Xs[LL];
    __shared__ float A[BB];
    const int t = threadIdx.x;

    const int s = stu[n];
    const int c = cour[n];
    const float* __restrict__ src = csa + ((size_t)s * CC + c) * (size_t)(LL * BB);

    // Slice is contiguous & 4000B-aligned from a 16B-aligned base -> float4 loads.
    for (int i = t; i < (LL * BB) / 4; i += 128) {
        ((float4*)V)[i] = ((const float4*)src)[i];
    }
    if (t < LL) Xs[t] = X[(size_t)n * LL + t];
    __syncthreads();

    // Fused column softmax over L + weighted reduce with X:
    // A[b] = sum_l X[l]*exp(v[l,b]-m) / sum_l exp(v[l,b]-m)
    if (t < BB) {
        float m = -INFINITY;
        for (int l = 0; l < LL; ++l) m = fmaxf(m, V[l * BB + t]);
        float ssum = 0.f, tsum = 0.f;
        for (int l = 0; l < LL; ++l) {
            const float e = __expf(V[l * BB + t] - m);
            ssum += e;
            tsum += e * Xs[l];
        }
        A[t] = tsum / ssum;
    }
    __syncthreads();

    // Y[c] = sum_b A[b] * Q[c,b]; out = (1-slide)*Y + guess*(1-Y)
    if (t < CC) {
        float y = 0.f;
        #pragma unroll
        for (int b = 0; b < BB; ++b) y += A[b] * Q[t * BB + b];
        const float g  = 1.f / (1.f + __expf(-guess_[t]));
        const float sl = 1.f / (1.f + __expf(-slide_[t]));
        out[(size_t)n * CC + t] = (1.f - sl) * y + g * (1.f - y);
    }
}

extern "C" void kernel_launch(void* const* d_in, const int* in_sizes, int n_in,
                              void* d_out, int out_size, void* d_ws, size_t ws_size,
                              hipStream_t stream) {
    const float* X      = (const float*)d_in[0];
    const int*   stu    = (const int*)  d_in[1];
    const int*   cour   = (const int*)  d_in[2];
    const float* csa    = (const float*)d_in[3];
    const float* P      = (const float*)d_in[4];
    const float* D      = (const float*)d_in[5];
    const float* P_A    = (const float*)d_in[6];
    const float* P_B    = (const float*)d_in[7];
    const float* P_C    = (const float*)d_in[8];
    const float* D_A    = (const float*)d_in[9];
    const float* D_B    = (const float*)d_in[10];
    const float* guess_ = (const float*)d_in[11];
    const float* slide_ = (const float*)d_in[12];
    float* out = (float*)d_out;
    float* Q   = (float*)d_ws;   // C*B floats = 8000 B of scratch

    const int N = in_sizes[1];   // 16384

    compute_q_kernel<<<1, 256, 0, stream>>>(P, D, P_A, P_B, P_C, D_A, D_B, Q);
    main_kernel<<<N, 128, 0, stream>>>(X, stu, cour, csa, Q, guess_, slide_, out);
}

// Round 2
// 40.883 us; speedup vs baseline: 1.0226x; 1.0226x over previous
//
#include <hip/hip_runtime.h>
#include <hip/hip_bf16.h>
#include <math.h>

// Problem constants: S=1000, C=100, L=50, B=20, K=64, N=16384
#define CC 100
#define LL 50
#define BB 20
#define KK 64
#define SPB 4   // samples per block in main kernel

// ---------------------------------------------------------------------------
// Kernel 1: Q2[c,b] = (1 - sigmoid(slide_[c]) - sigmoid(guess_[c])) *
//                     sum_k softmaxrow(P*P_A+P_B)[k,c] * (softmaxcol(D*D_A+D_B) @ P_C)[k,b]
//           G[c]   = sigmoid(guess_[c])
// Single block, 256 threads, softmaxes parallelized 4 lanes per row/col.
// ---------------------------------------------------------------------------
__global__ __launch_bounds__(256) void compute_q_kernel(
    const float* __restrict__ P, const float* __restrict__ D,
    const float* __restrict__ P_A, const float* __restrict__ P_B,
    const float* __restrict__ P_C, const float* __restrict__ D_A,
    const float* __restrict__ D_B, const float* __restrict__ guess_,
    const float* __restrict__ slide_,
    float* __restrict__ Q2, float* __restrict__ G)
{
    __shared__ float Pm[KK * CC];    // 6400 floats
    __shared__ float Dm[KK * BB];    // 1280
    __shared__ float E [KK * BB];
    __shared__ float PCs[BB * BB];   // 400
    __shared__ float scale[CC];
    const int t = threadIdx.x;

    for (int i = t; i < KK * CC; i += 256) Pm[i] = fmaf(P[i], P_A[i], P_B[i]);
    for (int i = t; i < KK * BB; i += 256) Dm[i] = fmaf(D[i], D_A[i], D_B[i]);
    for (int i = t; i < BB * BB; i += 256) PCs[i] = P_C[i];
    if (t < CC) {
        const float g  = 1.f / (1.f + __expf(-guess_[t]));
        const float sl = 1.f / (1.f + __expf(-slide_[t]));
        scale[t] = 1.f - sl - g;
        G[t] = g;
    }
    __syncthreads();

    // Row softmax of Pm over C=100: 4 lanes per row, 25 cols each.
    {
        const int r = t >> 2, q = t & 3;
        float* row = Pm + r * CC + q * 25;
        float m = -INFINITY;
        #pragma unroll
        for (int i = 0; i < 25; ++i) m = fmaxf(m, row[i]);
        m = fmaxf(m, __shfl_xor(m, 1));
        m = fmaxf(m, __shfl_xor(m, 2));
        float s = 0.f;
        #pragma unroll
        for (int i = 0; i < 25; ++i) { float e = __expf(row[i] - m); row[i] = e; s += e; }
        s += __shfl_xor(s, 1);
        s += __shfl_xor(s, 2);
        const float inv = 1.f / s;
        #pragma unroll
        for (int i = 0; i < 25; ++i) row[i] *= inv;
    }
    // Column softmax of Dm over K=64: 4 lanes per column, 16 k's each.
    if (t < 4 * BB) {
        const int b = t >> 2, q = t & 3;
        float m = -INFINITY;
        #pragma unroll
        for (int k = q * 16; k < q * 16 + 16; ++k) m = fmaxf(m, Dm[k * BB + b]);
        m = fmaxf(m, __shfl_xor(m, 1));
        m = fmaxf(m, __shfl_xor(m, 2));
        float s = 0.f;
        #pragma unroll
        for (int k = q * 16; k < q * 16 + 16; ++k) { float e = __expf(Dm[k * BB + b] - m); Dm[k * BB + b] = e; s += e; }
        s += __shfl_xor(s, 1);
        s += __shfl_xor(s, 2);
        const float inv = 1.f / s;
        #pragma unroll
        for (int k = q * 16; k < q * 16 + 16; ++k) Dm[k * BB + b] *= inv;
    }
    __syncthreads();

    // E = Dm @ P_C : [K,B]
    for (int i = t; i < KK * BB; i += 256) {
        const int k = i / BB, b = i % BB;
        float acc = 0.f;
        #pragma unroll
        for (int j = 0; j < BB; ++j) acc = fmaf(Dm[k * BB + j], PCs[j * BB + b], acc);
        E[i] = acc;
    }
    __syncthreads();

    // Q2[c,b] = scale[c] * sum_k Pm[k,c] * E[k,b]
    for (int i = t; i < CC * BB; i += 256) {
        const int c = i / BB, b = i % BB;
        float acc = 0.f;
        #pragma unroll
        for (int k = 0; k < KK; ++k) acc = fmaf(Pm[k * CC + c], E[k * BB + b], acc);
        Q2[i] = acc * scale[c];
    }
}

// ---------------------------------------------------------------------------
// Kernel 2: 4 samples per 256-thread block. Per sample: gather [50,20] slice,
// single-pass column softmax (no max-sub: |csa| < ~6.5, exp safe in fp32)
// fused with the X-weighted reduce, then matvec vs pre-scaled Q2 + G.
// ---------------------------------------------------------------------------
__global__ __launch_bounds__(256) void main_kernel(
    const float* __restrict__ X, const int* __restrict__ stu,
    const int* __restrict__ cour, const float* __restrict__ csa,
    const float* __restrict__ Q2, const float* __restrict__ G,
    float* __restrict__ out, int N)
{
    __shared__ float V[SPB][LL * BB];   // 4 x 4000 B
    __shared__ float Xs[SPB][LL + 2];
    __shared__ float A[SPB][BB];
    __shared__ float Q2s[CC * (BB + 1)]; // padded stride 21 -> conflict-free matvec
    __shared__ float Gs[CC];

    const int n0 = blockIdx.x * SPB;
    const int t  = threadIdx.x;

    // Stage Q2 (padded) and G.
    for (int i = t; i < CC * BB; i += 256) {
        const int c = i / BB, b = i % BB;
        Q2s[c * (BB + 1) + b] = Q2[i];
    }
    if (t < CC) Gs[t] = G[t];

    // Gather the 4 csa slices (each contiguous 4000 B, float4-aligned).
    #pragma unroll
    for (int j = 0; j < SPB; ++j) {
        const int n = n0 + j;
        if (n < N && t < (LL * BB) / 4) {
            const int s = stu[n], c = cour[n];
            const float4* src = (const float4*)(csa + ((size_t)s * CC + c) * (size_t)(LL * BB));
            ((float4*)V[j])[t] = src[t];
        }
    }
    // X rows (200 B each, 8B-aligned): 4*25 float2 loads.
    if (t < SPB * (LL / 2)) {
        const int j = t / (LL / 2), i = t % (LL / 2);
        const int n = n0 + j;
        if (n < N) {
            const float2 v = ((const float2*)(X + (size_t)n * LL))[i];
            Xs[j][2 * i]     = v.x;
            Xs[j][2 * i + 1] = v.y;
        }
    }
    __syncthreads();

    // Wave w owns sample j=w: lanes 0..19 each do one column's fused
    // softmax-reduce: A[b] = sum_l X[l]*exp(v[l,b]) / sum_l exp(v[l,b]).
    {
        const int w = t >> 6;       // 0..3
        const int lane = t & 63;
        if (lane < BB && n0 + w < N) {
            float ssum = 0.f, tsum = 0.f;
            #pragma unroll 5
            for (int l = 0; l < LL; ++l) {
                const float e = __expf(V[w][l * BB + lane]);
                ssum += e;
                tsum = fmaf(e, Xs[w][l], tsum);
            }
            A[w][lane] = tsum / ssum;
        }
    }
    __syncthreads();

    // out[n,c] = dot(A[j], Q2s[c,:]) + G[c]
    for (int i = t; i < SPB * CC; i += 256) {
        const int j = i / CC, c = i % CC;
        const int n = n0 + j;
        if (n < N) {
            float y = 0.f;
            #pragma unroll
            for (int b = 0; b < BB; ++b) y = fmaf(A[j][b], Q2s[c * (BB + 1) + b], y);
            out[(size_t)n * CC + c] = y + Gs[c];
        }
    }
}

extern "C" void kernel_launch(void* const* d_in, const int* in_sizes, int n_in,
                              void* d_out, int out_size, void* d_ws, size_t ws_size,
                              hipStream_t stream) {
    const float* X      = (const float*)d_in[0];
    const int*   stu    = (const int*)  d_in[1];
    const int*   cour   = (const int*)  d_in[2];
    const float* csa    = (const float*)d_in[3];
    const float* P      = (const float*)d_in[4];
    const float* D      = (const float*)d_in[5];
    const float* P_A    = (const float*)d_in[6];
    const float* P_B    = (const float*)d_in[7];
    const float* P_C    = (const float*)d_in[8];
    const float* D_A    = (const float*)d_in[9];
    const float* D_B    = (const float*)d_in[10];
    const float* guess_ = (const float*)d_in[11];
    const float* slide_ = (const float*)d_in[12];
    float* out = (float*)d_out;
    float* Q2  = (float*)d_ws;            // C*B floats
    float* G   = (float*)d_ws + CC * BB;  // C floats

    const int N = in_sizes[1];   // 16384

    compute_q_kernel<<<1, 256, 0, stream>>>(P, D, P_A, P_B, P_C, D_A, D_B,
                                            guess_, slide_, Q2, G);
    const int grid = (N + SPB - 1) / SPB;
    main_kernel<<<grid, 256, 0, stream>>>(X, stu, cour, csa, Q2, G, out, N);
}

// Round 3
// 36.408 us; speedup vs baseline: 1.1483x; 1.1229x over previous
//
#include <hip/hip_runtime.h>
#include <hip/hip_bf16.h>
#include <math.h>

// Problem constants: S=1000, C=100, L=50, B=20, K=64, N=16384
#define CC 100
#define LL 50
#define BB 20
#define KK 64

// ---------------------------------------------------------------------------
// Kernel 1: Q2[c,b] = (1 - sigmoid(slide_[c]) - sigmoid(guess_[c])) *
//                     [softmaxrow(P*P_A+P_B)^T @ (softmaxcol(D*D_A+D_B) @ P_C)](c,b)
//           G[c]   = sigmoid(guess_[c])
// Single block, 256 threads.
// ---------------------------------------------------------------------------
__global__ __launch_bounds__(256) void compute_q_kernel(
    const float* __restrict__ P, const float* __restrict__ D,
    const float* __restrict__ P_A, const float* __restrict__ P_B,
    const float* __restrict__ P_C, const float* __restrict__ D_A,
    const float* __restrict__ D_B, const float* __restrict__ guess_,
    const float* __restrict__ slide_,
    float* __restrict__ Q2, float* __restrict__ G)
{
    __shared__ float Pm[KK * CC];
    __shared__ float Dm[KK * BB];
    __shared__ float E [KK * BB];
    __shared__ float PCs[BB * BB];
    __shared__ float scale[CC];
    const int t = threadIdx.x;

    for (int i = t; i < KK * CC; i += 256) Pm[i] = fmaf(P[i], P_A[i], P_B[i]);
    for (int i = t; i < KK * BB; i += 256) Dm[i] = fmaf(D[i], D_A[i], D_B[i]);
    for (int i = t; i < BB * BB; i += 256) PCs[i] = P_C[i];
    if (t < CC) {
        const float g  = 1.f / (1.f + __expf(-guess_[t]));
        const float sl = 1.f / (1.f + __expf(-slide_[t]));
        scale[t] = 1.f - sl - g;
        G[t] = g;
    }
    __syncthreads();

    // Row softmax of Pm over C=100: 4 lanes per row, 25 cols each.
    {
        const int r = t >> 2, q = t & 3;
        float* row = Pm + r * CC + q * 25;
        float m = -INFINITY;
        #pragma unroll
        for (int i = 0; i < 25; ++i) m = fmaxf(m, row[i]);
        m = fmaxf(m, __shfl_xor(m, 1));
        m = fmaxf(m, __shfl_xor(m, 2));
        float s = 0.f;
        #pragma unroll
        for (int i = 0; i < 25; ++i) { float e = __expf(row[i] - m); row[i] = e; s += e; }
        s += __shfl_xor(s, 1);
        s += __shfl_xor(s, 2);
        const float inv = 1.f / s;
        #pragma unroll
        for (int i = 0; i < 25; ++i) row[i] *= inv;
    }
    // Column softmax of Dm over K=64: 4 lanes per column.
    if (t < 4 * BB) {
        const int b = t >> 2, q = t & 3;
        float m = -INFINITY;
        #pragma unroll
        for (int k = q * 16; k < q * 16 + 16; ++k) m = fmaxf(m, Dm[k * BB + b]);
        m = fmaxf(m, __shfl_xor(m, 1));
        m = fmaxf(m, __shfl_xor(m, 2));
        float s = 0.f;
        #pragma unroll
        for (int k = q * 16; k < q * 16 + 16; ++k) { float e = __expf(Dm[k * BB + b] - m); Dm[k * BB + b] = e; s += e; }
        s += __shfl_xor(s, 1);
        s += __shfl_xor(s, 2);
        const float inv = 1.f / s;
        #pragma unroll
        for (int k = q * 16; k < q * 16 + 16; ++k) Dm[k * BB + b] *= inv;
    }
    __syncthreads();

    // E = Dm @ P_C : [K,B]
    for (int i = t; i < KK * BB; i += 256) {
        const int k = i / BB, b = i % BB;
        float acc = 0.f;
        #pragma unroll
        for (int j = 0; j < BB; ++j) acc = fmaf(Dm[k * BB + j], PCs[j * BB + b], acc);
        E[i] = acc;
    }
    __syncthreads();

    // Q2[c,b] = scale[c] * sum_k Pm[k,c] * E[k,b]
    for (int i = t; i < CC * BB; i += 256) {
        const int c = i / BB, b = i % BB;
        float acc = 0.f;
        #pragma unroll
        for (int k = 0; k < KK; ++k) acc = fmaf(Pm[k * CC + c], E[k * BB + b], acc);
        Q2[i] = acc * scale[c];
    }
}

// ---------------------------------------------------------------------------
// Kernel 2: ONE SAMPLE PER WAVE, no block-wide barriers. Each wave:
//   gather 4 KB slice -> own LDS region -> fused column-softmax+X-reduce on
//   60 lanes (3 L-chunks, combined via shfl) -> 100-wide matvec with A
//   broadcast via shfl, Q2/G straight from cache -> coalesced store.
// 4 waves/block, ~17 KB LDS -> 32 waves/CU, each an independent memory stream.
// ---------------------------------------------------------------------------
__global__ __launch_bounds__(256) void main_kernel(
    const float* __restrict__ X, const int* __restrict__ stu,
    const int* __restrict__ cour, const float* __restrict__ csa,
    const float* __restrict__ Q2, const float* __restrict__ G,
    float* __restrict__ out, int N)
{
    __shared__ __align__(16) float V[4][LL * BB];   // 4 x 4000 B, one per wave
    __shared__ float Xs[4][LL];
    const int t = threadIdx.x;
    const int w = t >> 6, lane = t & 63;
    const int n = blockIdx.x * 4 + w;
    if (n >= N) return;   // wave-uniform; no barriers anywhere

    const int s = stu[n], c = cour[n];                 // wave-uniform -> s_load
    const float4* __restrict__ src4 =
        (const float4*)(csa + ((size_t)s * CC + c) * (size_t)(LL * BB));
    float4* V4 = (float4*)V[w];

    // 250 float4 per slice: 4 rounds of 64 lanes.
    #pragma unroll
    for (int r = 0; r < 4; ++r) {
        const int idx = r * 64 + lane;
        if (idx < (LL * BB) / 4) V4[idx] = src4[idx];
    }
    if (lane < LL) Xs[w][lane] = X[(size_t)n * LL + lane];

    // Per-wave LDS producer->consumer: drain lgkm, fence the scheduler.
    asm volatile("s_waitcnt lgkmcnt(0)" ::: "memory");
    __builtin_amdgcn_sched_barrier(0);

    // Fused column softmax over L (no max-sub: |csa|<~6.5, fp32-safe) + X reduce.
    // lane = b + 20*g, g=0..2 owns an L-chunk; lanes 60..63 idle.
    const int b = lane % BB;
    const int g = lane / BB;          // 0..3
    float ssum = 0.f, tsum = 0.f;
    if (g < 3) {
        const int l0 = (g == 0) ? 0 : (g == 1) ? 17 : 34;
        const int l1 = (g == 0) ? 17 : (g == 1) ? 34 : LL;
        for (int l = l0; l < l1; ++l) {
            const float e = __expf(V[w][l * BB + b]);
            ssum += e;
            tsum = fmaf(e, Xs[w][l], tsum);
        }
    }
    // Combine the 3 partials for this lane's b (absolute-lane shfl).
    const float sT = __shfl(ssum, b) + __shfl(ssum, b + BB) + __shfl(ssum, b + 2 * BB);
    const float tT = __shfl(tsum, b) + __shfl(tsum, b + BB) + __shfl(tsum, b + 2 * BB);
    const float Aval = tT / sT;       // lane b (b<20) holds A[b]

    // Matvec: lane handles c0=lane, c1=64+lane (lane<36). Q2 rows from cache.
    float4 q0[5], q1[5];
    const float4* Q2v0 = (const float4*)(Q2 + lane * BB);
    #pragma unroll
    for (int k = 0; k < 5; ++k) q0[k] = Q2v0[k];
    if (lane < CC - 64) {
        const float4* Q2v1 = (const float4*)(Q2 + (64 + lane) * BB);
        #pragma unroll
        for (int k = 0; k < 5; ++k) q1[k] = Q2v1[k];
    }
    float y0 = 0.f, y1 = 0.f;
    #pragma unroll
    for (int bb = 0; bb < BB; ++bb) {
        const float a = __shfl(Aval, bb);          // readlane broadcast
        y0 = fmaf(a, ((const float*)q0)[bb], y0);
        y1 = fmaf(a, ((const float*)q1)[bb], y1);
    }
    float* orow = out + (size_t)n * CC;
    orow[lane] = y0 + G[lane];
    if (lane < CC - 64) orow[64 + lane] = y1 + G[64 + lane];
}

extern "C" void kernel_launch(void* const* d_in, const int* in_sizes, int n_in,
                              void* d_out, int out_size, void* d_ws, size_t ws_size,
                              hipStream_t stream) {
    const float* X      = (const float*)d_in[0];
    const int*   stu    = (const int*)  d_in[1];
    const int*   cour   = (const int*)  d_in[2];
    const float* csa    = (const float*)d_in[3];
    const float* P      = (const float*)d_in[4];
    const float* D      = (const float*)d_in[5];
    const float* P_A    = (const float*)d_in[6];
    const float* P_B    = (const float*)d_in[7];
    const float* P_C    = (const float*)d_in[8];
    const float* D_A    = (const float*)d_in[9];
    const float* D_B    = (const float*)d_in[10];
    const float* guess_ = (const float*)d_in[11];
    const float* slide_ = (const float*)d_in[12];
    float* out = (float*)d_out;
    float* Q2  = (float*)d_ws;            // C*B floats
    float* G   = (float*)d_ws + CC * BB;  // C floats

    const int N = in_sizes[1];   // 16384

    compute_q_kernel<<<1, 256, 0, stream>>>(P, D, P_A, P_B, P_C, D_A, D_B,
                                            guess_, slide_, Q2, G);
    main_kernel<<<(N + 3) / 4, 256, 0, stream>>>(X, stu, cour, csa, Q2, G, out, N);
}

// Round 4
// 33.462 us; speedup vs baseline: 1.2494x; 1.0880x over previous
//
#include <hip/hip_runtime.h>
#include <hip/hip_bf16.h>
#include <math.h>

// Problem constants: S=1000, C=100, L=50, B=20, K=64, N=16384
#define CC 100
#define LL 50
#define BB 20
#define KK 64

// ---------------------------------------------------------------------------
// Kernel 1: Q2[c,b] = (1 - sig(slide_[c]) - sig(guess_[c])) *
//                     [softmaxrow(P*P_A+P_B)^T @ (softmaxcol(D*D_A+D_B) @ P_C)](c,b)
//           G[c]   = sig(guess_[c])
// Single block, 256 threads. Q2 phase: lane-per-c, E broadcast via readlane
// (2 LDS reads per k instead of 40).
// ---------------------------------------------------------------------------
__global__ __launch_bounds__(256) void compute_q_kernel(
    const float* __restrict__ P, const float* __restrict__ D,
    const float* __restrict__ P_A, const float* __restrict__ P_B,
    const float* __restrict__ P_C, const float* __restrict__ D_A,
    const float* __restrict__ D_B, const float* __restrict__ guess_,
    const float* __restrict__ slide_,
    float* __restrict__ Q2, float* __restrict__ G)
{
    __shared__ float Pm[KK * CC];    // 6400
    __shared__ float Dm[KK * BB];    // 1280
    __shared__ float E [KK * BB];
    __shared__ float PCs[BB * BB];
    __shared__ float scale[CC];
    const int t = threadIdx.x;

    // Vectorized staging: 6400/4 = 1600 float4 (P), 1280/4 = 320 (D).
    {
        const float4* P4  = (const float4*)P;
        const float4* PA4 = (const float4*)P_A;
        const float4* PB4 = (const float4*)P_B;
        float4* Pm4 = (float4*)Pm;
        for (int i = t; i < (KK * CC) / 4; i += 256) {
            const float4 p = P4[i], a = PA4[i], bb = PB4[i];
            float4 r;
            r.x = fmaf(p.x, a.x, bb.x); r.y = fmaf(p.y, a.y, bb.y);
            r.z = fmaf(p.z, a.z, bb.z); r.w = fmaf(p.w, a.w, bb.w);
            Pm4[i] = r;
        }
        const float4* D4  = (const float4*)D;
        const float4* DA4 = (const float4*)D_A;
        const float4* DB4 = (const float4*)D_B;
        float4* Dm4 = (float4*)Dm;
        for (int i = t; i < (KK * BB) / 4; i += 256) {
            const float4 p = D4[i], a = DA4[i], bb = DB4[i];
            float4 r;
            r.x = fmaf(p.x, a.x, bb.x); r.y = fmaf(p.y, a.y, bb.y);
            r.z = fmaf(p.z, a.z, bb.z); r.w = fmaf(p.w, a.w, bb.w);
            Dm4[i] = r;
        }
        const float4* PC4 = (const float4*)P_C;
        float4* PCs4 = (float4*)PCs;
        for (int i = t; i < (BB * BB) / 4; i += 256) PCs4[i] = PC4[i];
    }
    if (t < CC) {
        const float g  = 1.f / (1.f + __expf(-guess_[t]));
        const float sl = 1.f / (1.f + __expf(-slide_[t]));
        scale[t] = 1.f - sl - g;
        G[t] = g;
    }
    __syncthreads();

    // Row softmax of Pm over C=100: 4 lanes per row, 25 cols each.
    {
        const int r = t >> 2, q = t & 3;
        float* row = Pm + r * CC + q * 25;
        float m = -INFINITY;
        #pragma unroll
        for (int i = 0; i < 25; ++i) m = fmaxf(m, row[i]);
        m = fmaxf(m, __shfl_xor(m, 1));
        m = fmaxf(m, __shfl_xor(m, 2));
        float s = 0.f;
        #pragma unroll
        for (int i = 0; i < 25; ++i) { float e = __expf(row[i] - m); row[i] = e; s += e; }
        s += __shfl_xor(s, 1);
        s += __shfl_xor(s, 2);
        const float inv = 1.f / s;
        #pragma unroll
        for (int i = 0; i < 25; ++i) row[i] *= inv;
    }
    // Column softmax of Dm over K=64: 4 lanes per column.
    if (t < 4 * BB) {
        const int b = t >> 2, q = t & 3;
        float m = -INFINITY;
        #pragma unroll
        for (int k = q * 16; k < q * 16 + 16; ++k) m = fmaxf(m, Dm[k * BB + b]);
        m = fmaxf(m, __shfl_xor(m, 1));
        m = fmaxf(m, __shfl_xor(m, 2));
        float s = 0.f;
        #pragma unroll
        for (int k = q * 16; k < q * 16 + 16; ++k) { float e = __expf(Dm[k * BB + b] - m); Dm[k * BB + b] = e; s += e; }
        s += __shfl_xor(s, 1);
        s += __shfl_xor(s, 2);
        const float inv = 1.f / s;
        #pragma unroll
        for (int k = q * 16; k < q * 16 + 16; ++k) Dm[k * BB + b] *= inv;
    }
    __syncthreads();

    // E = Dm @ P_C : [K,B]   (2560 FMAs total, cheap)
    for (int i = t; i < KK * BB; i += 256) {
        const int k = i / BB, b = i % BB;
        float acc = 0.f;
        #pragma unroll
        for (int j = 0; j < BB; ++j) acc = fmaf(Dm[k * BB + j], PCs[j * BB + b], acc);
        E[i] = acc;
    }
    __syncthreads();

    // Q2 phase: waves 0,1; lane -> one column c. Per k: 2 coalesced/broadcast
    // LDS reads + 20 readlane-broadcast FMAs into 20 register accumulators.
    if (t < 128) {
        const int w = t >> 6, lane = t & 63;
        const int craw = w * 50 + lane;
        const int c = craw < CC ? craw : CC - 1;
        float acc[BB];
        #pragma unroll
        for (int j = 0; j < BB; ++j) acc[j] = 0.f;
        for (int k = 0; k < KK; ++k) {
            const float pm = Pm[k * CC + c];
            const float ev = E[k * BB + (lane % BB)];   // lanes 0..19 hold E[k][j]
            #pragma unroll
            for (int j = 0; j < BB; ++j) {
                const float ej = __uint_as_float(
                    __builtin_amdgcn_readlane(__float_as_uint(ev), j));
                acc[j] = fmaf(pm, ej, acc[j]);
            }
        }
        if (craw < CC) {
            const float sc = scale[c];
            #pragma unroll
            for (int j = 0; j < BB; ++j) Q2[c * BB + j] = acc[j] * sc;
        }
    }
}

// ---------------------------------------------------------------------------
// Kernel 2: one sample per wave, NO LDS, no barriers. Lane = b + 20*g:
// g<3 owns an L-chunk of column b, loads csa directly to registers,
// single-pass exp (|csa|<~6.5, fp32-safe) + X-weighted reduce; 3 partials
// combined via shuffles; matvec vs Q2 with readlane broadcast of A.
// Lanes 60..63 mirror g=0 (avoids OOB), never read in the combine.
// ---------------------------------------------------------------------------
__global__ __launch_bounds__(256) void main_kernel(
    const float* __restrict__ X, const int* __restrict__ stu,
    const int* __restrict__ cour, const float* __restrict__ csa,
    const float* __restrict__ Q2, const float* __restrict__ G,
    float* __restrict__ out, int N)
{
    const int t = threadIdx.x;
    const int w = t >> 6, lane = t & 63;
    const int n = blockIdx.x * 4 + w;
    if (n >= N) return;

    const int s = stu[n], c = cour[n];            // wave-uniform
    const float* __restrict__ base = csa + ((size_t)s * CC + c) * (size_t)(LL * BB);
    const float* __restrict__ xrow = X + (size_t)n * LL;

    const int b = lane % BB;
    const int g = lane / BB;                      // 0..3
    const int l0 = (g >= 3) ? 0 : g * 17;         // g3 mirrors g0
    const bool has17 = (g != 2);                  // g2 covers l=34..49 (16)

    // Hoist independent matvec operands: Q2 rows + G (L2-hot after block 0).
    const int c1ok = (lane < CC - 64);
    float4 q0[5], q1[5];
    {
        const float4* Q2v0 = (const float4*)(Q2 + lane * BB);
        #pragma unroll
        for (int k = 0; k < 5; ++k) q0[k] = Q2v0[k];
        if (c1ok) {
            const float4* Q2v1 = (const float4*)(Q2 + (64 + lane) * BB);
            #pragma unroll
            for (int k = 0; k < 5; ++k) q1[k] = Q2v1[k];
        }
    }
    const float g0v = G[lane];
    const float g1v = c1ok ? G[64 + lane] : 0.f;

    // Issue all slice loads before any use.
    float vbuf[16], xbuf[16];
    #pragma unroll
    for (int i = 0; i < 16; ++i) {
        vbuf[i] = base[(l0 + i) * BB + b];
        xbuf[i] = xrow[l0 + i];
    }
    float v16 = 0.f, x16 = 0.f;
    if (has17) {
        v16 = base[(l0 + 16) * BB + b];
        x16 = xrow[l0 + 16];
    }

    float ssum = 0.f, tsum = 0.f;
    #pragma unroll
    for (int i = 0; i < 16; ++i) {
        const float e = __expf(vbuf[i]);
        ssum += e;
        tsum = fmaf(e, xbuf[i], tsum);
    }
    if (has17) {
        const float e = __expf(v16);
        ssum += e;
        tsum = fmaf(e, x16, tsum);
    }

    // Combine the 3 chunk partials for this lane's b.
    const float sT = __shfl(ssum, b) + __shfl(ssum, b + BB) + __shfl(ssum, b + 2 * BB);
    const float tT = __shfl(tsum, b) + __shfl(tsum, b + BB) + __shfl(tsum, b + 2 * BB);
    const float Aval = tT / sT;                   // lane j<20 holds A[j]

    // out[n,c] = sum_b A[b]*Q2[c,b] + G[c]
    float y0 = 0.f, y1 = 0.f;
    #pragma unroll
    for (int bb = 0; bb < BB; ++bb) {
        const float a = __uint_as_float(
            __builtin_amdgcn_readlane(__float_as_uint(Aval), bb));
        y0 = fmaf(a, ((const float*)q0)[bb], y0);
        y1 = fmaf(a, ((const float*)q1)[bb], y1);
    }
    float* orow = out + (size_t)n * CC;
    orow[lane] = y0 + g0v;
    if (c1ok) orow[64 + lane] = y1 + g1v;
}

extern "C" void kernel_launch(void* const* d_in, const int* in_sizes, int n_in,
                              void* d_out, int out_size, void* d_ws, size_t ws_size,
                              hipStream_t stream) {
    const float* X      = (const float*)d_in[0];
    const int*   stu    = (const int*)  d_in[1];
    const int*   cour   = (const int*)  d_in[2];
    const float* csa    = (const float*)d_in[3];
    const float* P      = (const float*)d_in[4];
    const float* D      = (const float*)d_in[5];
    const float* P_A    = (const float*)d_in[6];
    const float* P_B    = (const float*)d_in[7];
    const float* P_C    = (const float*)d_in[8];
    const float* D_A    = (const float*)d_in[9];
    const float* D_B    = (const float*)d_in[10];
    const float* guess_ = (const float*)d_in[11];
    const float* slide_ = (const float*)d_in[12];
    float* out = (float*)d_out;
    float* Q2  = (float*)d_ws;            // C*B floats
    float* G   = (float*)d_ws + CC * BB;  // C floats

    const int N = in_sizes[1];   // 16384

    compute_q_kernel<<<1, 256, 0, stream>>>(P, D, P_A, P_B, P_C, D_A, D_B,
                                            guess_, slide_, Q2, G);
    main_kernel<<<(N + 3) / 4, 256, 0, stream>>>(X, stu, cour, csa, Q2, G, out, N);
}

// Round 5
// 32.643 us; speedup vs baseline: 1.2808x; 1.0251x over previous
//
#include <hip/hip_runtime.h>
#include <hip/hip_bf16.h>
#include <math.h>

// Problem constants: S=1000, C=100, L=50, B=20, K=64, N=16384
#define CC 100
#define LL 50
#define BB 20
#define KK 64

// ---------------------------------------------------------------------------
// Kernel 1: grid = CC blocks (one per course c), 256 threads (4 waves).
//   Q2[c,b] = (1 - sig(slide_[c]) - sig(guess_[c])) *
//             sum_k Pm[k,c] * E[k,b],   Pm = softmax_row(P), E = softmax_col(D) @ P_C
//   G[c]   = sig(guess_[c])
// All inputs are tiny and L2-hot; redundant per-block recompute of the
// shared pieces (Dm, E, rowsums) is cheaper than a serial single block.
// No max-subtraction: P,D ~ N(0,1)-scale -> exp safe in fp32 (softmax is
// shift-invariant; validated rounds 1-4 with the same trick on csa).
// ---------------------------------------------------------------------------
__global__ __launch_bounds__(256) void compute_q_kernel(
    const float* __restrict__ P, const float* __restrict__ D,
    const float* __restrict__ P_A, const float* __restrict__ P_B,
    const float* __restrict__ P_C, const float* __restrict__ D_A,
    const float* __restrict__ D_B, const float* __restrict__ guess_,
    const float* __restrict__ slide_,
    float* __restrict__ Q2, float* __restrict__ G)
{
    const int c    = blockIdx.x;        // 0..99
    const int t    = threadIdx.x;
    const int w    = t >> 6;            // wave 0..3 -> owns b in [5w, 5w+5)
    const int lane = t & 63;            // == k (K=64)

    __shared__ float PCs[BB * BB];      // 400 floats
    __shared__ float rowsum_sh[KK];

    // Stage P_C (100 float4, coalesced).
    if (t < (BB * BB) / 4) ((float4*)PCs)[t] = ((const float4*)P_C)[t];

    // Rowsums of exp(P*P_A+P_B): thread (k=t>>2, q=t&3) sums 25 consecutive c'.
    {
        const int k = t >> 2, q = t & 3;
        const float* __restrict__ pr  = P   + k * CC + q * 25;
        const float* __restrict__ par = P_A + k * CC + q * 25;
        const float* __restrict__ pbr = P_B + k * CC + q * 25;
        float s = 0.f;
        #pragma unroll
        for (int i = 0; i < 25; ++i) s += __expf(fmaf(pr[i], par[i], pbr[i]));
        s += __shfl_xor(s, 1);
        s += __shfl_xor(s, 2);
        if (q == 0) rowsum_sh[k] = s;
    }

    // Dm row k in registers (each wave redundantly): exp(D*D_A+D_B), then
    // column-normalize via 64-lane butterfly sums per b.
    float dm[BB];
    {
        const float4* d4  = (const float4*)(D   + lane * BB);
        const float4* da4 = (const float4*)(D_A + lane * BB);
        const float4* db4 = (const float4*)(D_B + lane * BB);
        #pragma unroll
        for (int i = 0; i < 5; ++i) {
            const float4 dv = d4[i], av = da4[i], bv = db4[i];
            dm[4 * i + 0] = __expf(fmaf(dv.x, av.x, bv.x));
            dm[4 * i + 1] = __expf(fmaf(dv.y, av.y, bv.y));
            dm[4 * i + 2] = __expf(fmaf(dv.z, av.z, bv.z));
            dm[4 * i + 3] = __expf(fmaf(dv.w, av.w, bv.w));
        }
    }
    #pragma unroll
    for (int b = 0; b < BB; ++b) {
        float s = dm[b];
        s += __shfl_xor(s, 1);  s += __shfl_xor(s, 2);  s += __shfl_xor(s, 4);
        s += __shfl_xor(s, 8);  s += __shfl_xor(s, 16); s += __shfl_xor(s, 32);
        dm[b] *= (1.f / s);     // Dm[k][b]
    }
    __syncthreads();            // PCs + rowsum_sh ready

    // E[k][b] for this wave's 5 b's (PCs reads are wave-uniform -> broadcast).
    float ev[5];
    #pragma unroll
    for (int j = 0; j < 5; ++j) {
        const int b = 5 * w + j;
        float acc = 0.f;
        #pragma unroll
        for (int jj = 0; jj < BB; ++jj) acc = fmaf(dm[jj], PCs[jj * BB + b], acc);
        ev[j] = acc;
    }

    // Pm[k,c] for this block's c (scattered stride-CC loads, L2/L1-hot).
    const float ps = fmaf(P[lane * CC + c], P_A[lane * CC + c], P_B[lane * CC + c]);
    const float pm = __expf(ps) / rowsum_sh[lane];

    // Q2[c, 5w+j] = scale * sum_k pm[k] * E[k, 5w+j] via butterfly reduce.
    float qv[5];
    #pragma unroll
    for (int j = 0; j < 5; ++j) {
        float v = pm * ev[j];
        v += __shfl_xor(v, 1);  v += __shfl_xor(v, 2);  v += __shfl_xor(v, 4);
        v += __shfl_xor(v, 8);  v += __shfl_xor(v, 16); v += __shfl_xor(v, 32);
        qv[j] = v;
    }
    if (lane == 0) {
        const float g  = 1.f / (1.f + __expf(-guess_[c]));
        const float sl = 1.f / (1.f + __expf(-slide_[c]));
        const float scale = 1.f - sl - g;
        #pragma unroll
        for (int j = 0; j < 5; ++j) Q2[c * BB + 5 * w + j] = qv[j] * scale;
        if (w == 0) G[c] = g;
    }
}

// ---------------------------------------------------------------------------
// Kernel 2: one sample per wave, no LDS, no barriers. Lane = b + 20*g:
// g<3 owns an L-chunk of column b; csa loads issued FIRST (HBM-cold long
// pole), X via one load + shfl, Q2/G hoisted behind the gather. Single-pass
// exp (no max-sub) + X-weighted reduce; 3 partials combined via shfl;
// matvec with readlane-broadcast A.
// ---------------------------------------------------------------------------
__global__ __launch_bounds__(256) void main_kernel(
    const float* __restrict__ X, const int* __restrict__ stu,
    const int* __restrict__ cour, const float* __restrict__ csa,
    const float* __restrict__ Q2, const float* __restrict__ G,
    float* __restrict__ out, int N)
{
    const int t = threadIdx.x;
    const int w = t >> 6, lane = t & 63;
    const int n = blockIdx.x * 4 + w;
    if (n >= N) return;

    const int s = stu[n], c = cour[n];            // wave-uniform -> s_load
    const float* __restrict__ base = csa + ((size_t)s * CC + c) * (size_t)(LL * BB);

    const int b = lane % BB;
    const int g = lane / BB;                      // 0..3 (g3 mirrors g0, ignored)
    const int l0 = (g >= 3) ? 0 : g * 17;
    const bool has17 = (g != 2);                  // g2 covers l=34..49 (16 rows)

    // --- Issue the cold gather first: 16 (+1) column loads. ---
    float vbuf[16];
    #pragma unroll
    for (int i = 0; i < 16; ++i) vbuf[i] = base[(l0 + i) * BB + b];
    float v16 = 0.f;
    if (has17) v16 = base[(l0 + 16) * BB + b];

    // X row: one coalesced load, distributed by shuffle.
    const float xv = (lane < LL) ? X[(size_t)n * LL + lane] : 0.f;

    // Hot operands (L2/L1): Q2 rows + G.
    const int c1ok = (lane < CC - 64);
    float4 q0[5], q1[5];
    {
        const float4* Q2v0 = (const float4*)(Q2 + lane * BB);
        #pragma unroll
        for (int k = 0; k < 5; ++k) q0[k] = Q2v0[k];
        if (c1ok) {
            const float4* Q2v1 = (const float4*)(Q2 + (64 + lane) * BB);
            #pragma unroll
            for (int k = 0; k < 5; ++k) q1[k] = Q2v1[k];
        }
    }
    const float g0v = G[lane];
    const float g1v = c1ok ? G[64 + lane] : 0.f;

    // Fused column softmax + X-weighted reduce.
    float ssum = 0.f, tsum = 0.f;
    #pragma unroll
    for (int i = 0; i < 16; ++i) {
        const float e = __expf(vbuf[i]);
        ssum += e;
        tsum = fmaf(e, __shfl(xv, l0 + i), tsum);
    }
    if (has17) {
        const float e = __expf(v16);
        ssum += e;
        tsum = fmaf(e, __shfl(xv, l0 + 16), tsum);
    }

    // Combine the 3 chunk partials for this lane's b.
    const float sT = __shfl(ssum, b) + __shfl(ssum, b + BB) + __shfl(ssum, b + 2 * BB);
    const float tT = __shfl(tsum, b) + __shfl(tsum, b + BB) + __shfl(tsum, b + 2 * BB);
    const float Aval = tT / sT;                   // lane j<20 holds A[j]

    // out[n,c] = sum_b A[b]*Q2[c,b] + G[c]
    float y0 = 0.f, y1 = 0.f;
    #pragma unroll
    for (int bb = 0; bb < BB; ++bb) {
        const float a = __uint_as_float(
            __builtin_amdgcn_readlane(__float_as_uint(Aval), bb));
        y0 = fmaf(a, ((const float*)q0)[bb], y0);
        y1 = fmaf(a, ((const float*)q1)[bb], y1);
    }
    float* orow = out + (size_t)n * CC;
    orow[lane] = y0 + g0v;
    if (c1ok) orow[64 + lane] = y1 + g1v;
}

extern "C" void kernel_launch(void* const* d_in, const int* in_sizes, int n_in,
                              void* d_out, int out_size, void* d_ws, size_t ws_size,
                              hipStream_t stream) {
    const float* X      = (const float*)d_in[0];
    const int*   stu    = (const int*)  d_in[1];
    const int*   cour   = (const int*)  d_in[2];
    const float* csa    = (const float*)d_in[3];
    const float* P      = (const float*)d_in[4];
    const float* D      = (const float*)d_in[5];
    const float* P_A    = (const float*)d_in[6];
    const float* P_B    = (const float*)d_in[7];
    const float* P_C    = (const float*)d_in[8];
    const float* D_A    = (const float*)d_in[9];
    const float* D_B    = (const float*)d_in[10];
    const float* guess_ = (const float*)d_in[11];
    const float* slide_ = (const float*)d_in[12];
    float* out = (float*)d_out;
    float* Q2  = (float*)d_ws;            // C*B floats
    float* G   = (float*)d_ws + CC * BB;  // C floats

    const int N = in_sizes[1];   // 16384

    compute_q_kernel<<<CC, 256, 0, stream>>>(P, D, P_A, P_B, P_C, D_A, D_B,
                                             guess_, slide_, Q2, G);
    main_kernel<<<(N + 3) / 4, 256, 0, stream>>>(X, stu, cour, csa, Q2, G, out, N);
}

// Round 6
// 31.186 us; speedup vs baseline: 1.3406x; 1.0467x over previous
//
#include <hip/hip_runtime.h>
#include <hip/hip_bf16.h>
#include <math.h>

// Problem constants: S=1000, C=100, L=50, B=20, K=64, N=16384
#define CC 100
#define LL 50
#define BB 20
#define KK 64

// ---------------------------------------------------------------------------
// Kernel 1: grid = CC blocks (one per course c), 256 threads (4 waves).
//   Q2[c,b] = (1 - sig(slide_[c]) - sig(guess_[c])) * sum_k Pm[k,c] * E[k,b]
//   G[c]   = sig(guess_[c])
// (unchanged from round 5 — measured minor)
// ---------------------------------------------------------------------------
__global__ __launch_bounds__(256) void compute_q_kernel(
    const float* __restrict__ P, const float* __restrict__ D,
    const float* __restrict__ P_A, const float* __restrict__ P_B,
    const float* __restrict__ P_C, const float* __restrict__ D_A,
    const float* __restrict__ D_B, const float* __restrict__ guess_,
    const float* __restrict__ slide_,
    float* __restrict__ Q2, float* __restrict__ G)
{
    const int c    = blockIdx.x;
    const int t    = threadIdx.x;
    const int w    = t >> 6;
    const int lane = t & 63;            // == k

    __shared__ float PCs[BB * BB];
    __shared__ float rowsum_sh[KK];

    if (t < (BB * BB) / 4) ((float4*)PCs)[t] = ((const float4*)P_C)[t];

    {
        const int k = t >> 2, q = t & 3;
        const float* __restrict__ pr  = P   + k * CC + q * 25;
        const float* __restrict__ par = P_A + k * CC + q * 25;
        const float* __restrict__ pbr = P_B + k * CC + q * 25;
        float s = 0.f;
        #pragma unroll
        for (int i = 0; i < 25; ++i) s += __expf(fmaf(pr[i], par[i], pbr[i]));
        s += __shfl_xor(s, 1);
        s += __shfl_xor(s, 2);
        if (q == 0) rowsum_sh[k] = s;
    }

    float dm[BB];
    {
        const float4* d4  = (const float4*)(D   + lane * BB);
        const float4* da4 = (const float4*)(D_A + lane * BB);
        const float4* db4 = (const float4*)(D_B + lane * BB);
        #pragma unroll
        for (int i = 0; i < 5; ++i) {
            const float4 dv = d4[i], av = da4[i], bv = db4[i];
            dm[4 * i + 0] = __expf(fmaf(dv.x, av.x, bv.x));
            dm[4 * i + 1] = __expf(fmaf(dv.y, av.y, bv.y));
            dm[4 * i + 2] = __expf(fmaf(dv.z, av.z, bv.z));
            dm[4 * i + 3] = __expf(fmaf(dv.w, av.w, bv.w));
        }
    }
    #pragma unroll
    for (int b = 0; b < BB; ++b) {
        float s = dm[b];
        s += __shfl_xor(s, 1);  s += __shfl_xor(s, 2);  s += __shfl_xor(s, 4);
        s += __shfl_xor(s, 8);  s += __shfl_xor(s, 16); s += __shfl_xor(s, 32);
        dm[b] *= (1.f / s);
    }
    __syncthreads();

    float ev[5];
    #pragma unroll
    for (int j = 0; j < 5; ++j) {
        const int b = 5 * w + j;
        float acc = 0.f;
        #pragma unroll
        for (int jj = 0; jj < BB; ++jj) acc = fmaf(dm[jj], PCs[jj * BB + b], acc);
        ev[j] = acc;
    }

    const float ps = fmaf(P[lane * CC + c], P_A[lane * CC + c], P_B[lane * CC + c]);
    const float pm = __expf(ps) / rowsum_sh[lane];

    float qv[5];
    #pragma unroll
    for (int j = 0; j < 5; ++j) {
        float v = pm * ev[j];
        v += __shfl_xor(v, 1);  v += __shfl_xor(v, 2);  v += __shfl_xor(v, 4);
        v += __shfl_xor(v, 8);  v += __shfl_xor(v, 16); v += __shfl_xor(v, 32);
        qv[j] = v;
    }
    if (lane == 0) {
        const float g  = 1.f / (1.f + __expf(-guess_[c]));
        const float sl = 1.f / (1.f + __expf(-slide_[c]));
        const float scale = 1.f - sl - g;
        #pragma unroll
        for (int j = 0; j < 5; ++j) Q2[c * BB + 5 * w + j] = qv[j] * scale;
        if (w == 0) G[c] = g;
    }
}

// ---------------------------------------------------------------------------
// Kernel 2: TWO samples per wave (ILP x2), no LDS, no barriers.
// Lane = b + 20*g, g<3 owns an L-chunk of column b for BOTH samples.
// Both idx loads + both gathers issued up front (~8.6 KB in flight/wave);
// Q2/G register loads amortized across the two matvecs.
// ---------------------------------------------------------------------------
__global__ __launch_bounds__(256) void main_kernel(
    const float* __restrict__ X, const int* __restrict__ stu,
    const int* __restrict__ cour, const float* __restrict__ csa,
    const float* __restrict__ Q2, const float* __restrict__ G,
    float* __restrict__ out, int N)
{
    const int t = threadIdx.x;
    const int w = t >> 6, lane = t & 63;
    const int n0 = blockIdx.x * 8 + 2 * w;
    const int n1 = n0 + 1;
    if (n0 >= N) return;
    const bool hasB = (n1 < N);

    // Both samples' indices (wave-uniform scalar loads) and bases.
    const int sA = stu[n0], cA = cour[n0];
    const int sB = hasB ? stu[n1] : sA;
    const int cB = hasB ? cour[n1] : cA;
    const float* __restrict__ baseA = csa + ((size_t)sA * CC + cA) * (size_t)(LL * BB);
    const float* __restrict__ baseB = csa + ((size_t)sB * CC + cB) * (size_t)(LL * BB);

    const int b = lane % BB;
    const int g = lane / BB;                      // 0..3 (g3 mirrors g0, unused)
    const int l0 = (g >= 3) ? 0 : g * 17;
    const bool has17 = (g != 2);                  // g2 covers 16 rows

    // --- Issue both cold gathers first: 2 x (16+1) column loads. ---
    float va[16], vb[16];
    #pragma unroll
    for (int i = 0; i < 16; ++i) va[i] = baseA[(l0 + i) * BB + b];
    #pragma unroll
    for (int i = 0; i < 16; ++i) vb[i] = baseB[(l0 + i) * BB + b];
    float va16 = 0.f, vb16 = 0.f;
    if (has17) {
        va16 = baseA[(l0 + 16) * BB + b];
        vb16 = baseB[(l0 + 16) * BB + b];
    }

    // X rows: one coalesced load each, distributed by shuffle.
    const float xvA = (lane < LL) ? X[(size_t)n0 * LL + lane] : 0.f;
    const float xvB = (hasB && lane < LL) ? X[(size_t)n1 * LL + lane] : 0.f;

    // Hot operands (L1/L2): Q2 rows + G, shared by both samples.
    const int c1ok = (lane < CC - 64);
    float4 q0[5], q1[5];
    {
        const float4* Q2v0 = (const float4*)(Q2 + lane * BB);
        #pragma unroll
        for (int k = 0; k < 5; ++k) q0[k] = Q2v0[k];
        if (c1ok) {
            const float4* Q2v1 = (const float4*)(Q2 + (64 + lane) * BB);
            #pragma unroll
            for (int k = 0; k < 5; ++k) q1[k] = Q2v1[k];
        }
    }
    const float g0v = G[lane];
    const float g1v = c1ok ? G[64 + lane] : 0.f;

    // Fused column softmax + X-weighted reduce, both samples.
    float ssA = 0.f, tsA = 0.f, ssB = 0.f, tsB = 0.f;
    #pragma unroll
    for (int i = 0; i < 16; ++i) {
        const float eA = __expf(va[i]);
        const float eB = __expf(vb[i]);
        ssA += eA; ssB += eB;
        tsA = fmaf(eA, __shfl(xvA, l0 + i), tsA);
        tsB = fmaf(eB, __shfl(xvB, l0 + i), tsB);
    }
    if (has17) {
        const float eA = __expf(va16);
        const float eB = __expf(vb16);
        ssA += eA; ssB += eB;
        tsA = fmaf(eA, __shfl(xvA, l0 + 16), tsA);
        tsB = fmaf(eB, __shfl(xvB, l0 + 16), tsB);
    }

    // Combine 3 chunk partials per b for both samples.
    const float sTA = __shfl(ssA, b) + __shfl(ssA, b + BB) + __shfl(ssA, b + 2 * BB);
    const float tTA = __shfl(tsA, b) + __shfl(tsA, b + BB) + __shfl(tsA, b + 2 * BB);
    const float sTB = __shfl(ssB, b) + __shfl(ssB, b + BB) + __shfl(ssB, b + 2 * BB);
    const float tTB = __shfl(tsB, b) + __shfl(tsB, b + BB) + __shfl(tsB, b + 2 * BB);
    const float AvA = tTA / sTA;                  // lane j<20 holds A[n0][j]
    const float AvB = tTB / sTB;                  // lane j<20 holds A[n1][j]

    // Matvecs: out[n,c] = sum_b A[b]*Q2[c,b] + G[c], Q2 regs shared.
    float y0A = 0.f, y1A = 0.f, y0B = 0.f, y1B = 0.f;
    #pragma unroll
    for (int bb = 0; bb < BB; ++bb) {
        const float aA = __uint_as_float(
            __builtin_amdgcn_readlane(__float_as_uint(AvA), bb));
        const float aB = __uint_as_float(
            __builtin_amdgcn_readlane(__float_as_uint(AvB), bb));
        const float qv0 = ((const float*)q0)[bb];
        const float qv1 = ((const float*)q1)[bb];
        y0A = fmaf(aA, qv0, y0A);  y1A = fmaf(aA, qv1, y1A);
        y0B = fmaf(aB, qv0, y0B);  y1B = fmaf(aB, qv1, y1B);
    }
    float* orowA = out + (size_t)n0 * CC;
    orowA[lane] = y0A + g0v;
    if (c1ok) orowA[64 + lane] = y1A + g1v;
    if (hasB) {
        float* orowB = out + (size_t)n1 * CC;
        orowB[lane] = y0B + g0v;
        if (c1ok) orowB[64 + lane] = y1B + g1v;
    }
}

extern "C" void kernel_launch(void* const* d_in, const int* in_sizes, int n_in,
                              void* d_out, int out_size, void* d_ws, size_t ws_size,
                              hipStream_t stream) {
    const float* X      = (const float*)d_in[0];
    const int*   stu    = (const int*)  d_in[1];
    const int*   cour   = (const int*)  d_in[2];
    const float* csa    = (const float*)d_in[3];
    const float* P      = (const float*)d_in[4];
    const float* D      = (const float*)d_in[5];
    const float* P_A    = (const float*)d_in[6];
    const float* P_B    = (const float*)d_in[7];
    const float* P_C    = (const float*)d_in[8];
    const float* D_A    = (const float*)d_in[9];
    const float* D_B    = (const float*)d_in[10];
    const float* guess_ = (const float*)d_in[11];
    const float* slide_ = (const float*)d_in[12];
    float* out = (float*)d_out;
    float* Q2  = (float*)d_ws;            // C*B floats
    float* G   = (float*)d_ws + CC * BB;  // C floats

    const int N = in_sizes[1];   // 16384

    compute_q_kernel<<<CC, 256, 0, stream>>>(P, D, P_A, P_B, P_C, D_A, D_B,
                                             guess_, slide_, Q2, G);
    main_kernel<<<(N + 7) / 8, 256, 0, stream>>>(X, stu, cour, csa, Q2, G, out, N);
}